// Round 1
// baseline (294.236 us; speedup 1.0000x reference)
//
#include <hip/hip_runtime.h>

#define HW 1024
#define CC 256
#define NB 32
constexpr float INV_T = 1.0f / 0.07f;

// ---------------- Kernel 1: batched GEMM ----------------
// N[b,i,k] = (1/T) * sum_c B2[b,c,i] * A2[b,c,k]
// A2,B2 are [C, HW] per batch, contiguous in the last dim.
__global__ __launch_bounds__(256) void gemm_kernel(const float* __restrict__ A,
                                                   const float* __restrict__ Bm,
                                                   float* __restrict__ N) {
    int blk = blockIdx.x;
    int b = blk >> 8;           // 256 tiles per batch (16x16 of 64x64)
    int tile = blk & 255;
    int i0 = (tile >> 4) * 64;
    int k0 = (tile & 15) * 64;
    const float* A2 = A + (size_t)b * CC * HW;
    const float* B2 = Bm + (size_t)b * CC * HW;
    float* Nb = N + (size_t)b * HW * HW;

    __shared__ float Bs[16][64];
    __shared__ float As[16][64];

    int t = threadIdx.x;
    int lr = t >> 4;            // load row 0..15
    int lc = (t & 15) * 4;      // load col (float4)

    int ty = t >> 4;            // 0..15 -> output rows i0 + ty*4 + a
    int tx = t & 15;            // 0..15 -> output cols k0 + tx*4 + b

    float acc[4][4] = {};

    for (int c0 = 0; c0 < CC; c0 += 16) {
        float4 bv = *reinterpret_cast<const float4*>(&B2[(size_t)(c0 + lr) * HW + i0 + lc]);
        float4 av = *reinterpret_cast<const float4*>(&A2[(size_t)(c0 + lr) * HW + k0 + lc]);
        __syncthreads();
        *reinterpret_cast<float4*>(&Bs[lr][lc]) = bv;
        *reinterpret_cast<float4*>(&As[lr][lc]) = av;
        __syncthreads();
#pragma unroll
        for (int cc = 0; cc < 16; ++cc) {
            float bvr[4], avr[4];
            float4 bq = *reinterpret_cast<const float4*>(&Bs[cc][ty * 4]);
            float4 aq = *reinterpret_cast<const float4*>(&As[cc][tx * 4]);
            bvr[0] = bq.x; bvr[1] = bq.y; bvr[2] = bq.z; bvr[3] = bq.w;
            avr[0] = aq.x; avr[1] = aq.y; avr[2] = aq.z; avr[3] = aq.w;
#pragma unroll
            for (int a = 0; a < 4; ++a)
#pragma unroll
                for (int bb = 0; bb < 4; ++bb)
                    acc[a][bb] += bvr[a] * avr[bb];
        }
    }
#pragma unroll
    for (int a = 0; a < 4; ++a) {
        float4 v;
        v.x = acc[a][0] * INV_T;
        v.y = acc[a][1] * INV_T;
        v.z = acc[a][2] * INV_T;
        v.w = acc[a][3] * INV_T;
        *reinterpret_cast<float4*>(&Nb[(size_t)(i0 + ty * 4 + a) * HW + k0 + tx * 4]) = v;
    }
}

// ---------------- Kernel 2a: row stats ----------------
// one wave per row; rmax[row], rsuminv[row] = 1/sum_k exp(N[row,k]-rmax)
__global__ __launch_bounds__(256) void rowstats_kernel(const float* __restrict__ N,
                                                       float* __restrict__ rmax,
                                                       float* __restrict__ rsuminv) {
    int wid = threadIdx.x >> 6;
    int lane = threadIdx.x & 63;
    size_t row = (size_t)blockIdx.x * 4 + wid;   // 0 .. NB*HW-1
    const float* Np = N + row * HW;
    float4 v[4];
    float m = -INFINITY;
#pragma unroll
    for (int u = 0; u < 4; ++u) {
        v[u] = *reinterpret_cast<const float4*>(&Np[lane * 4 + u * 256]);
        m = fmaxf(m, fmaxf(fmaxf(v[u].x, v[u].y), fmaxf(v[u].z, v[u].w)));
    }
#pragma unroll
    for (int off = 32; off; off >>= 1) m = fmaxf(m, __shfl_xor(m, off));
    float s = 0.f;
#pragma unroll
    for (int u = 0; u < 4; ++u) {
        s += __expf(v[u].x - m) + __expf(v[u].y - m) +
             __expf(v[u].z - m) + __expf(v[u].w - m);
    }
#pragma unroll
    for (int off = 32; off; off >>= 1) s += __shfl_xor(s, off);
    if (lane == 0) {
        rmax[row] = m;
        rsuminv[row] = 1.0f / s;
    }
}

// ---------------- Kernel 2b: column partial stats ----------------
// grid = NB*4*8: (b, kgroup of 256, ichunk of 128). Online (max,sum).
__global__ __launch_bounds__(256) void colpart_kernel(const float* __restrict__ N,
                                                      float* __restrict__ pm,
                                                      float* __restrict__ ps) {
    int blk = blockIdx.x;
    int chunk = blk & 7;
    int bk = blk >> 3;          // 0..127
    int b = bk >> 2;
    int k = ((bk & 3) << 8) + threadIdx.x;
    const float* Nb = N + (size_t)b * HW * HW + (size_t)chunk * 128 * HW;
    float m = -INFINITY, s = 0.f;
    for (int i = 0; i < 128; ++i) {
        float x = Nb[(size_t)i * HW + k];
        float mn = fmaxf(m, x);
        s = s * __expf(m - mn) + __expf(x - mn);
        m = mn;
    }
    size_t idx = (size_t)chunk * (NB * HW) + (size_t)b * HW + k;
    pm[idx] = m;
    ps[idx] = s;
}

// ---------------- Kernel 2c: combine column partials ----------------
__global__ __launch_bounds__(256) void colcombine_kernel(const float* __restrict__ pm,
                                                         const float* __restrict__ ps,
                                                         float* __restrict__ cmax,
                                                         float* __restrict__ csuminv) {
    int idx = blockIdx.x * 256 + threadIdx.x;  // 0 .. NB*HW-1
    float m = -INFINITY;
#pragma unroll
    for (int ch = 0; ch < 8; ++ch) m = fmaxf(m, pm[ch * (NB * HW) + idx]);
    float s = 0.f;
#pragma unroll
    for (int ch = 0; ch < 8; ++ch) s += ps[ch * (NB * HW) + idx] * __expf(pm[ch * (NB * HW) + idx] - m);
    cmax[idx] = m;
    csuminv[idx] = 1.0f / s;
}

// ---------------- Kernel 3: P = softmax_row * softmax_col, transposed write ----------------
// out[b, t(k), i] = exp(N-rm_i)*rsinv_i * exp(N-cm_k)*csinv_k,  t(k)=(k%32)*32+k/32
__global__ __launch_bounds__(256) void final_kernel(const float* __restrict__ N,
                                                    const float* __restrict__ rm,
                                                    const float* __restrict__ rsi,
                                                    const float* __restrict__ cm,
                                                    const float* __restrict__ csi,
                                                    float* __restrict__ out) {
    int blk = blockIdx.x;
    int b = blk >> 8;
    int tile = blk & 255;
    int i0 = (tile >> 4) * 64;
    int k0 = (tile & 15) * 64;
    const float* Nb = N + (size_t)b * HW * HW;
    float* outb = out + (size_t)b * HW * HW;
    const float* rmb = rm + b * HW;
    const float* rsib = rsi + b * HW;
    const float* cmb = cm + b * HW;
    const float* csib = csi + b * HW;

    __shared__ float tileP[64][65];

    int t = threadIdx.x;
    int tr = t >> 4;            // 0..15
    int tc4 = (t & 15) * 4;     // 0..60

    // column stats for this thread's 4 k's (reused across rr)
    float4 cm4 = *reinterpret_cast<const float4*>(&cmb[k0 + tc4]);
    float4 cs4 = *reinterpret_cast<const float4*>(&csib[k0 + tc4]);

#pragma unroll
    for (int rr = 0; rr < 4; ++rr) {
        int il = tr + rr * 16;
        int i = i0 + il;
        float rmax = rmb[i];
        float rsinv = rsib[i];
        float4 v = *reinterpret_cast<const float4*>(&Nb[(size_t)i * HW + k0 + tc4]);
        float x[4] = {v.x, v.y, v.z, v.w};
        float cmv[4] = {cm4.x, cm4.y, cm4.z, cm4.w};
        float csv[4] = {cs4.x, cs4.y, cs4.z, cs4.w};
#pragma unroll
        for (int j = 0; j < 4; ++j) {
            tileP[il][tc4 + j] = __expf(x[j] - rmax) * rsinv * __expf(x[j] - cmv[j]) * csv[j];
        }
    }
    __syncthreads();
#pragma unroll
    for (int rr = 0; rr < 4; ++rr) {
        int kl = tr + rr * 16;
        int k = k0 + kl;
        int tk = ((k & 31) << 5) | (k >> 5);
        float4 v;
        v.x = tileP[tc4 + 0][kl];
        v.y = tileP[tc4 + 1][kl];
        v.z = tileP[tc4 + 2][kl];
        v.w = tileP[tc4 + 3][kl];
        *reinterpret_cast<float4*>(&outb[(size_t)tk * HW + i0 + tc4]) = v;
    }
}

extern "C" void kernel_launch(void* const* d_in, const int* in_sizes, int n_in,
                              void* d_out, int out_size, void* d_ws, size_t ws_size,
                              hipStream_t stream) {
    const float* A = (const float*)d_in[0];   // feature_A [32,256,32,32]
    const float* Bm = (const float*)d_in[1];  // feature_B [32,256,32,32]
    float* out = (float*)d_out;

    // workspace layout (floats)
    float* ws = (float*)d_ws;
    const size_t n_elems = (size_t)NB * HW * HW;       // 33.5M
    const size_t stat_n = (size_t)NB * HW;             // 32768
    float* N = ws;
    float* rmax = N + n_elems;
    float* rsuminv = rmax + stat_n;
    float* cmax = rsuminv + stat_n;
    float* csuminv = cmax + stat_n;
    float* pm = csuminv + stat_n;                      // 8 * stat_n
    float* ps = pm + 8 * stat_n;                       // 8 * stat_n

    hipLaunchKernelGGL(gemm_kernel, dim3(NB * 256), dim3(256), 0, stream, A, Bm, N);
    hipLaunchKernelGGL(rowstats_kernel, dim3(NB * HW / 4), dim3(256), 0, stream, N, rmax, rsuminv);
    hipLaunchKernelGGL(colpart_kernel, dim3(NB * 4 * 8), dim3(256), 0, stream, N, pm, ps);
    hipLaunchKernelGGL(colcombine_kernel, dim3(NB * HW / 256), dim3(256), 0, stream, pm, ps, cmax, csuminv);
    hipLaunchKernelGGL(final_kernel, dim3(NB * 256), dim3(256), 0, stream, N, rmax, rsuminv, cmax, csuminv, out);
}

// Round 2
// 176.421 us; speedup vs baseline: 1.6678x; 1.6678x over previous
//
#include <hip/hip_runtime.h>

#define HW 1024
#define CC 256
#define NB 32
constexpr float INV_T = 1.0f / 0.07f;

typedef __attribute__((ext_vector_type(8))) short short8;
typedef __attribute__((ext_vector_type(4))) float f32x4;

__device__ __forceinline__ ushort f2bf(float x) {
    uint32_t u = __float_as_uint(x);
    uint32_t r = (u + 0x7fffu + ((u >> 16) & 1u)) >> 16;
    return (ushort)r;
}
__device__ __forceinline__ float bf2f(ushort h) {
    return __uint_as_float(((uint32_t)h) << 16);
}

__device__ __forceinline__ void gload16(const void* g, void* l) {
    __builtin_amdgcn_global_load_lds(
        (const __attribute__((address_space(1))) uint32_t*)g,
        (__attribute__((address_space(3))) uint32_t*)l, 16, 0, 0);
}

// ---------------- Convert + transpose: X[b][c][hw] f32 -> hi/lo[b][hw][c] bf16 ----------------
__global__ __launch_bounds__(256) void convert_kernel(const float* __restrict__ X,
                                                      ushort* __restrict__ hi,
                                                      ushort* __restrict__ lo) {
    int blk = blockIdx.x;
    int b = blk >> 6;
    int tile = blk & 63;
    int c0 = (tile >> 4) * 64;   // 4 c-tiles
    int h0 = (tile & 15) * 64;   // 16 h-tiles

    __shared__ ushort Th[64][76];
    __shared__ ushort Tl[64][76];

    int tid = threadIdx.x;
    const float* Xb = X + ((size_t)b * CC + c0) * HW + h0;

#pragma unroll
    for (int p = 0; p < 4; ++p) {
        int cr = p * 16 + (tid >> 4);
        int hcol = (tid & 15) * 4;
        float4 v = *reinterpret_cast<const float4*>(&Xb[(size_t)cr * HW + hcol]);
        float xs[4] = {v.x, v.y, v.z, v.w};
#pragma unroll
        for (int j = 0; j < 4; ++j) {
            float x = xs[j];
            ushort h_ = f2bf(x);
            float hf = bf2f(h_);
            ushort l_ = f2bf(x - hf);
            Th[hcol + j][cr] = h_;
            Tl[hcol + j][cr] = l_;
        }
    }
    __syncthreads();
    size_t obase = ((size_t)b * HW + h0) * CC + c0;
#pragma unroll
    for (int q = 0; q < 4; ++q) {
        int hr = q * 16 + (tid >> 4);
        int cc = (tid & 15) * 4;
        ushort4 vh = *reinterpret_cast<const ushort4*>(&Th[hr][cc]);
        ushort4 vl = *reinterpret_cast<const ushort4*>(&Tl[hr][cc]);
        *reinterpret_cast<ushort4*>(&hi[obase + (size_t)hr * CC + cc]) = vh;
        *reinterpret_cast<ushort4*>(&lo[obase + (size_t)hr * CC + cc]) = vl;
    }
}

// ---------------- Kernel 1: batched split-bf16 MFMA GEMM ----------------
// N[b,i,k] = (1/T) * sum_c P[b,i,c] * Q[b,k,c],  P=feature_B^T, Q=feature_A^T (bf16 hi+lo)
// 3 passes: Phi*Qhi + Phi*Qlo + Plo*Qhi
__global__ __launch_bounds__(256) void gemm_mfma(const ushort* __restrict__ Phi,
                                                 const ushort* __restrict__ Plo,
                                                 const ushort* __restrict__ Qhi,
                                                 const ushort* __restrict__ Qlo,
                                                 float* __restrict__ Nout) {
    int bid = blockIdx.x;
    int swz = (bid & 7) * 256 + (bid >> 3);   // XCD swizzle, 2048 % 8 == 0 -> bijective
    int b = swz >> 6;
    int tile = swz & 63;
    int i0 = (tile >> 3) << 7;
    int k0 = (tile & 7) << 7;

    __shared__ ushort Ps[128 * 64];   // [row][64 c] bf16, XOR-swizzled rows (byte^((row&7)<<4))
    __shared__ ushort Qs[128 * 64];

    int tid = threadIdx.x;
    int lane = tid & 63;
    int w = tid >> 6;
    int wr = w >> 1, wc = w & 1;

    f32x4 acc[4][4];
#pragma unroll
    for (int fi = 0; fi < 4; ++fi)
#pragma unroll
        for (int fj = 0; fj < 4; ++fj)
#pragma unroll
            for (int r = 0; r < 4; ++r) acc[fi][fj][r] = 0.0f;

    size_t bbase = (size_t)b * HW * CC;

    for (int step = 0; step < 12; ++step) {
        int phase = step >> 2;
        int c0 = (step & 3) << 6;
        const ushort* Psrc = (phase == 2 ? Plo : Phi) + bbase + (size_t)i0 * CC + c0;
        const ushort* Qsrc = (phase == 1 ? Qlo : Qhi) + bbase + (size_t)k0 * CC + c0;
        __syncthreads();
#pragma unroll
        for (int is = 0; is < 4; ++is) {
            int o = is * 4096 + tid * 16;            // linear LDS byte offset
            int row = o >> 7;                        // 128-B rows
            int src = (o & 127) ^ ((row & 7) << 4);  // inverse-swizzled source byte-in-row
            gload16((const char*)Psrc + row * 512 + src, (char*)Ps + is * 4096 + w * 1024);
            gload16((const char*)Qsrc + row * 512 + src, (char*)Qs + is * 4096 + w * 1024);
        }
        __syncthreads();
#pragma unroll
        for (int kk = 0; kk < 2; ++kk) {
            short8 af[4], bfr[4];
#pragma unroll
            for (int f = 0; f < 4; ++f) {
                int rp = wr * 64 + f * 16 + (lane & 15);
                int cb = (kk * 64 + (lane >> 4) * 16) ^ ((rp & 7) << 4);
                af[f] = *(const short8*)((const char*)Ps + rp * 128 + cb);
                int rq = wc * 64 + f * 16 + (lane & 15);
                int cq = (kk * 64 + (lane >> 4) * 16) ^ ((rq & 7) << 4);
                bfr[f] = *(const short8*)((const char*)Qs + rq * 128 + cq);
            }
#pragma unroll
            for (int fi = 0; fi < 4; ++fi)
#pragma unroll
                for (int fj = 0; fj < 4; ++fj)
                    acc[fi][fj] = __builtin_amdgcn_mfma_f32_16x16x32_bf16(af[fi], bfr[fj], acc[fi][fj], 0, 0, 0);
        }
    }

    float* Nb = Nout + (size_t)b * HW * HW;
#pragma unroll
    for (int fi = 0; fi < 4; ++fi) {
        int i = i0 + wr * 64 + fi * 16 + ((lane >> 4) << 2);
#pragma unroll
        for (int fj = 0; fj < 4; ++fj) {
            int k = k0 + wc * 64 + fj * 16 + (lane & 15);
#pragma unroll
            for (int r = 0; r < 4; ++r)
                Nb[(size_t)(i + r) * HW + k] = acc[fi][fj][r] * INV_T;
        }
    }
}

// ---------------- Kernel 2a: row stats ----------------
__global__ __launch_bounds__(256) void rowstats_kernel(const float* __restrict__ N,
                                                       float* __restrict__ rmax,
                                                       float* __restrict__ rsuminv) {
    int wid = threadIdx.x >> 6;
    int lane = threadIdx.x & 63;
    size_t row = (size_t)blockIdx.x * 4 + wid;
    const float* Np = N + row * HW;
    float4 v[4];
    float m = -INFINITY;
#pragma unroll
    for (int u = 0; u < 4; ++u) {
        v[u] = *reinterpret_cast<const float4*>(&Np[lane * 4 + u * 256]);
        m = fmaxf(m, fmaxf(fmaxf(v[u].x, v[u].y), fmaxf(v[u].z, v[u].w)));
    }
#pragma unroll
    for (int off = 32; off; off >>= 1) m = fmaxf(m, __shfl_xor(m, off));
    float s = 0.f;
#pragma unroll
    for (int u = 0; u < 4; ++u) {
        s += __expf(v[u].x - m) + __expf(v[u].y - m) +
             __expf(v[u].z - m) + __expf(v[u].w - m);
    }
#pragma unroll
    for (int off = 32; off; off >>= 1) s += __shfl_xor(s, off);
    if (lane == 0) {
        rmax[row] = m;
        rsuminv[row] = 1.0f / s;
    }
}

// ---------------- Kernel 2b: column partial stats ----------------
__global__ __launch_bounds__(256) void colpart_kernel(const float* __restrict__ N,
                                                      float* __restrict__ pm,
                                                      float* __restrict__ ps) {
    int blk = blockIdx.x;
    int chunk = blk & 7;
    int bk = blk >> 3;
    int b = bk >> 2;
    int k = ((bk & 3) << 8) + threadIdx.x;
    const float* Nb = N + (size_t)b * HW * HW + (size_t)chunk * 128 * HW;
    float m = -INFINITY, s = 0.f;
    for (int i = 0; i < 128; ++i) {
        float x = Nb[(size_t)i * HW + k];
        float mn = fmaxf(m, x);
        s = s * __expf(m - mn) + __expf(x - mn);
        m = mn;
    }
    size_t idx = (size_t)chunk * (NB * HW) + (size_t)b * HW + k;
    pm[idx] = m;
    ps[idx] = s;
}

// ---------------- Kernel 2c: combine column partials ----------------
__global__ __launch_bounds__(256) void colcombine_kernel(const float* __restrict__ pm,
                                                         const float* __restrict__ ps,
                                                         float* __restrict__ cmax,
                                                         float* __restrict__ csuminv) {
    int idx = blockIdx.x * 256 + threadIdx.x;
    float m = -INFINITY;
#pragma unroll
    for (int ch = 0; ch < 8; ++ch) m = fmaxf(m, pm[ch * (NB * HW) + idx]);
    float s = 0.f;
#pragma unroll
    for (int ch = 0; ch < 8; ++ch) s += ps[ch * (NB * HW) + idx] * __expf(pm[ch * (NB * HW) + idx] - m);
    cmax[idx] = m;
    csuminv[idx] = 1.0f / s;
}

// ---------------- Kernel 3: P = softmax_row * softmax_col, transposed write ----------------
__global__ __launch_bounds__(256) void final_kernel(const float* __restrict__ N,
                                                    const float* __restrict__ rm,
                                                    const float* __restrict__ rsi,
                                                    const float* __restrict__ cm,
                                                    const float* __restrict__ csi,
                                                    float* __restrict__ out) {
    int blk = blockIdx.x;
    int b = blk >> 8;
    int tile = blk & 255;
    int i0 = (tile >> 4) * 64;
    int k0 = (tile & 15) * 64;
    const float* Nb = N + (size_t)b * HW * HW;
    float* outb = out + (size_t)b * HW * HW;
    const float* rmb = rm + b * HW;
    const float* rsib = rsi + b * HW;
    const float* cmb = cm + b * HW;
    const float* csib = csi + b * HW;

    __shared__ float tileP[64][65];

    int t = threadIdx.x;
    int tr = t >> 4;
    int tc4 = (t & 15) * 4;

    float4 cm4 = *reinterpret_cast<const float4*>(&cmb[k0 + tc4]);
    float4 cs4 = *reinterpret_cast<const float4*>(&csib[k0 + tc4]);

#pragma unroll
    for (int rr = 0; rr < 4; ++rr) {
        int il = tr + rr * 16;
        int i = i0 + il;
        float rmax = rmb[i];
        float rsinv = rsib[i];
        float4 v = *reinterpret_cast<const float4*>(&Nb[(size_t)i * HW + k0 + tc4]);
        float x[4] = {v.x, v.y, v.z, v.w};
        float cmv[4] = {cm4.x, cm4.y, cm4.z, cm4.w};
        float csv[4] = {cs4.x, cs4.y, cs4.z, cs4.w};
#pragma unroll
        for (int j = 0; j < 4; ++j) {
            tileP[il][tc4 + j] = __expf(x[j] - rmax) * rsinv * __expf(x[j] - cmv[j]) * csv[j];
        }
    }
    __syncthreads();
#pragma unroll
    for (int rr = 0; rr < 4; ++rr) {
        int kl = tr + rr * 16;
        int k = k0 + kl;
        int tk = ((k & 31) << 5) | (k >> 5);
        float4 v;
        v.x = tileP[tc4 + 0][kl];
        v.y = tileP[tc4 + 1][kl];
        v.z = tileP[tc4 + 2][kl];
        v.w = tileP[tc4 + 3][kl];
        *reinterpret_cast<float4*>(&outb[(size_t)tk * HW + i0 + tc4]) = v;
    }
}

extern "C" void kernel_launch(void* const* d_in, const int* in_sizes, int n_in,
                              void* d_out, int out_size, void* d_ws, size_t ws_size,
                              hipStream_t stream) {
    const float* A = (const float*)d_in[0];   // feature_A [32,256,32,32]
    const float* Bm = (const float*)d_in[1];  // feature_B [32,256,32,32]
    float* out = (float*)d_out;

    float* ws = (float*)d_ws;
    const size_t n_elems = (size_t)NB * HW * HW;       // 33.5M
    const size_t stat_n = (size_t)NB * HW;             // 32768
    float* N = ws;
    float* rmax = N + n_elems;
    float* rsuminv = rmax + stat_n;
    float* cmax = rsuminv + stat_n;
    float* csuminv = cmax + stat_n;
    float* pm = csuminv + stat_n;                      // 8 * stat_n
    float* ps = pm + 8 * stat_n;                       // 8 * stat_n
    ushort* Qhi = (ushort*)(ps + 8 * stat_n);          // feature_A^T bf16 hi
    ushort* Qlo = Qhi + (size_t)NB * HW * CC;
    ushort* Phi = Qlo + (size_t)NB * HW * CC;          // feature_B^T bf16 hi
    ushort* Plo = Phi + (size_t)NB * HW * CC;

    hipLaunchKernelGGL(convert_kernel, dim3(NB * 64), dim3(256), 0, stream, A, Qhi, Qlo);
    hipLaunchKernelGGL(convert_kernel, dim3(NB * 64), dim3(256), 0, stream, Bm, Phi, Plo);
    hipLaunchKernelGGL(gemm_mfma, dim3(NB * 64), dim3(256), 0, stream, Phi, Plo, Qhi, Qlo, N);
    hipLaunchKernelGGL(rowstats_kernel, dim3(NB * HW / 4), dim3(256), 0, stream, N, rmax, rsuminv);
    hipLaunchKernelGGL(colpart_kernel, dim3(NB * 4 * 8), dim3(256), 0, stream, N, pm, ps);
    hipLaunchKernelGGL(colcombine_kernel, dim3(NB * HW / 256), dim3(256), 0, stream, pm, ps, cmax, csuminv);
    hipLaunchKernelGGL(final_kernel, dim3(NB * 256), dim3(256), 0, stream, N, rmax, rsuminv, cmax, csuminv, out);
}

// Round 3
// 171.851 us; speedup vs baseline: 1.7122x; 1.0266x over previous
//
#include <hip/hip_runtime.h>

#define HW 1024
#define CC 256
#define NB 32
constexpr float INV_T = 1.0f / 0.07f;

typedef __attribute__((ext_vector_type(8))) short short8;
typedef __attribute__((ext_vector_type(4))) float f32x4;

__device__ __forceinline__ ushort f2bf(float x) {
    uint32_t u = __float_as_uint(x);
    uint32_t r = (u + 0x7fffu + ((u >> 16) & 1u)) >> 16;
    return (ushort)r;
}
__device__ __forceinline__ float bf2f(ushort h) {
    return __uint_as_float(((uint32_t)h) << 16);
}

__device__ __forceinline__ void gload16(const void* g, void* l) {
    __builtin_amdgcn_global_load_lds(
        (const __attribute__((address_space(1))) uint32_t*)g,
        (__attribute__((address_space(3))) uint32_t*)l, 16, 0, 0);
}

// ---------------- Convert + transpose: X[b][c][hw] f32 -> hi/lo[b][hw][c] bf16 ----------------
// grid = 2 * NB * 64; first half processes A -> (Qhi,Qlo), second half B -> (Phi,Plo)
__global__ __launch_bounds__(256) void convert_kernel(const float* __restrict__ A,
                                                      const float* __restrict__ Bm,
                                                      ushort* __restrict__ Qhi,
                                                      ushort* __restrict__ Qlo,
                                                      ushort* __restrict__ Phi,
                                                      ushort* __restrict__ Plo) {
    int blk = blockIdx.x;
    int which = blk >= NB * 64;
    if (which) blk -= NB * 64;
    const float* X = which ? Bm : A;
    ushort* hi = which ? Phi : Qhi;
    ushort* lo = which ? Plo : Qlo;

    int b = blk >> 6;
    int tile = blk & 63;
    int c0 = (tile >> 4) * 64;   // 4 c-tiles
    int h0 = (tile & 15) * 64;   // 16 h-tiles

    __shared__ ushort Th[64][76];
    __shared__ ushort Tl[64][76];

    int tid = threadIdx.x;
    const float* Xb = X + ((size_t)b * CC + c0) * HW + h0;

#pragma unroll
    for (int p = 0; p < 4; ++p) {
        int cr = p * 16 + (tid >> 4);
        int hcol = (tid & 15) * 4;
        float4 v = *reinterpret_cast<const float4*>(&Xb[(size_t)cr * HW + hcol]);
        float xs[4] = {v.x, v.y, v.z, v.w};
#pragma unroll
        for (int j = 0; j < 4; ++j) {
            float x = xs[j];
            ushort h_ = f2bf(x);
            float hf = bf2f(h_);
            ushort l_ = f2bf(x - hf);
            Th[hcol + j][cr] = h_;
            Tl[hcol + j][cr] = l_;
        }
    }
    __syncthreads();
    size_t obase = ((size_t)b * HW + h0) * CC + c0;
#pragma unroll
    for (int q = 0; q < 4; ++q) {
        int hr = q * 16 + (tid >> 4);
        int cc = (tid & 15) * 4;
        ushort4 vh = *reinterpret_cast<const ushort4*>(&Th[hr][cc]);
        ushort4 vl = *reinterpret_cast<const ushort4*>(&Tl[hr][cc]);
        *reinterpret_cast<ushort4*>(&hi[obase + (size_t)hr * CC + cc]) = vh;
        *reinterpret_cast<ushort4*>(&lo[obase + (size_t)hr * CC + cc]) = vl;
    }
}

// ---------------- Kernel 1: batched split-bf16 MFMA GEMM + fused partial softmax stats -------
// N[b,i,k] = (1/T) * sum_c P[b,i,c] * Q[b,k,c]
// Epilogue writes per-64-col row partials (rpm,rps)[b][kt16][i] and
// per-64-row col partials (cpm,cps)[b][it16][k].
__global__ __launch_bounds__(256) void gemm_mfma(const ushort* __restrict__ Phi,
                                                 const ushort* __restrict__ Plo,
                                                 const ushort* __restrict__ Qhi,
                                                 const ushort* __restrict__ Qlo,
                                                 float* __restrict__ Nout,
                                                 float* __restrict__ rpm,
                                                 float* __restrict__ rps,
                                                 float* __restrict__ cpm,
                                                 float* __restrict__ cps) {
    int bid = blockIdx.x;
    int swz = (bid & 7) * 256 + (bid >> 3);   // XCD swizzle, 2048 % 8 == 0 -> bijective
    int b = swz >> 6;
    int tile = swz & 63;
    int i0 = (tile >> 3) << 7;
    int k0 = (tile & 7) << 7;

    __shared__ ushort Ps[128 * 64];   // XOR-swizzled rows (byte^((row&7)<<4))
    __shared__ ushort Qs[128 * 64];

    int tid = threadIdx.x;
    int lane = tid & 63;
    int w = tid >> 6;
    int wr = w >> 1, wc = w & 1;

    f32x4 acc[4][4];
#pragma unroll
    for (int fi = 0; fi < 4; ++fi)
#pragma unroll
        for (int fj = 0; fj < 4; ++fj)
#pragma unroll
            for (int r = 0; r < 4; ++r) acc[fi][fj][r] = 0.0f;

    size_t bbase = (size_t)b * HW * CC;

    for (int step = 0; step < 12; ++step) {
        int phase = step >> 2;
        int c0 = (step & 3) << 6;
        const ushort* Psrc = (phase == 2 ? Plo : Phi) + bbase + (size_t)i0 * CC + c0;
        const ushort* Qsrc = (phase == 1 ? Qlo : Qhi) + bbase + (size_t)k0 * CC + c0;
        __syncthreads();
#pragma unroll
        for (int is = 0; is < 4; ++is) {
            int o = is * 4096 + tid * 16;            // linear LDS byte offset
            int row = o >> 7;                        // 128-B rows
            int src = (o & 127) ^ ((row & 7) << 4);  // inverse-swizzled source byte-in-row
            gload16((const char*)Psrc + row * 512 + src, (char*)Ps + is * 4096 + w * 1024);
            gload16((const char*)Qsrc + row * 512 + src, (char*)Qs + is * 4096 + w * 1024);
        }
        __syncthreads();
#pragma unroll
        for (int kk = 0; kk < 2; ++kk) {
            short8 af[4], bfr[4];
#pragma unroll
            for (int f = 0; f < 4; ++f) {
                int rp = wr * 64 + f * 16 + (lane & 15);
                int cb = (kk * 64 + (lane >> 4) * 16) ^ ((rp & 7) << 4);
                af[f] = *(const short8*)((const char*)Ps + rp * 128 + cb);
                int rq = wc * 64 + f * 16 + (lane & 15);
                int cq = (kk * 64 + (lane >> 4) * 16) ^ ((rq & 7) << 4);
                bfr[f] = *(const short8*)((const char*)Qs + rq * 128 + cq);
            }
#pragma unroll
            for (int fi = 0; fi < 4; ++fi)
#pragma unroll
                for (int fj = 0; fj < 4; ++fj)
                    acc[fi][fj] = __builtin_amdgcn_mfma_f32_16x16x32_bf16(af[fi], bfr[fj], acc[fi][fj], 0, 0, 0);
        }
    }

    // ---- write N tile ----
    float* Nb = Nout + (size_t)b * HW * HW;
#pragma unroll
    for (int fi = 0; fi < 4; ++fi) {
        int i = i0 + wr * 64 + fi * 16 + ((lane >> 4) << 2);
#pragma unroll
        for (int fj = 0; fj < 4; ++fj) {
            int k = k0 + wc * 64 + fj * 16 + (lane & 15);
#pragma unroll
            for (int r = 0; r < 4; ++r)
                Nb[(size_t)(i + r) * HW + k] = acc[fi][fj][r] * INV_T;
        }
    }

    // ---- fused row partial stats (this wave's 64 rows x 64 cols) ----
    // value at acc[fi][fj][r]: row = i0+wr*64+fi*16+(lane>>4)*4+r, col = k0+wc*64+fj*16+(lane&15)
    int kt = (tile & 7) * 2 + wc;          // 0..15 column-block-of-64 index
    int it = (tile >> 3) * 2 + wr;         // 0..15 row-block-of-64 index
    size_t rbase = ((size_t)b * 16 + kt) * HW;
    size_t cbase = ((size_t)b * 16 + it) * HW;

#pragma unroll
    for (int fi = 0; fi < 4; ++fi) {
#pragma unroll
        for (int r = 0; r < 4; ++r) {
            float x0 = acc[fi][0][r] * INV_T;
            float x1 = acc[fi][1][r] * INV_T;
            float x2 = acc[fi][2][r] * INV_T;
            float x3 = acc[fi][3][r] * INV_T;
            float m = fmaxf(fmaxf(x0, x1), fmaxf(x2, x3));
#pragma unroll
            for (int off = 1; off < 16; off <<= 1) m = fmaxf(m, __shfl_xor(m, off));
            float s = __expf(x0 - m) + __expf(x1 - m) + __expf(x2 - m) + __expf(x3 - m);
#pragma unroll
            for (int off = 1; off < 16; off <<= 1) s += __shfl_xor(s, off);
            if ((lane & 15) == 0) {
                int i = i0 + wr * 64 + fi * 16 + ((lane >> 4) << 2) + r;
                rpm[rbase + i] = m;
                rps[rbase + i] = s;
            }
        }
    }

    // ---- fused col partial stats (this wave's 64 rows per col) ----
#pragma unroll
    for (int fj = 0; fj < 4; ++fj) {
        float m = -INFINITY;
#pragma unroll
        for (int fi = 0; fi < 4; ++fi)
#pragma unroll
            for (int r = 0; r < 4; ++r) m = fmaxf(m, acc[fi][fj][r] * INV_T);
        m = fmaxf(m, __shfl_xor(m, 16));
        m = fmaxf(m, __shfl_xor(m, 32));
        float s = 0.f;
#pragma unroll
        for (int fi = 0; fi < 4; ++fi)
#pragma unroll
            for (int r = 0; r < 4; ++r) s += __expf(acc[fi][fj][r] * INV_T - m);
        s += __shfl_xor(s, 16);
        s += __shfl_xor(s, 32);
        if (lane < 16) {
            int k = k0 + wc * 64 + fj * 16 + lane;
            cpm[cbase + k] = m;
            cps[cbase + k] = s;
        }
    }
}

// ---------------- Kernel 2: combine partials -> rmax/rsuminv, cmax/csuminv ----------------
// grid = 256 blocks x 256: blocks [0,128) rows, [128,256) cols
__global__ __launch_bounds__(256) void combine_kernel(const float* __restrict__ rpm,
                                                      const float* __restrict__ rps,
                                                      const float* __restrict__ cpm,
                                                      const float* __restrict__ cps,
                                                      float* __restrict__ rmax,
                                                      float* __restrict__ rsuminv,
                                                      float* __restrict__ cmax,
                                                      float* __restrict__ csuminv) {
    int blk = blockIdx.x;
    int iscol = blk >= 128;
    if (iscol) blk -= 128;
    int idx = blk * 256 + threadIdx.x;        // 0 .. NB*HW-1
    int b = idx >> 10;
    int e = idx & 1023;
    const float* pm = iscol ? cpm : rpm;
    const float* ps = iscol ? cps : rps;
    size_t base = (size_t)b * 16 * HW + e;
    float m = -INFINITY;
#pragma unroll
    for (int t = 0; t < 16; ++t) m = fmaxf(m, pm[base + (size_t)t * HW]);
    float s = 0.f;
#pragma unroll
    for (int t = 0; t < 16; ++t) s += ps[base + (size_t)t * HW] * __expf(pm[base + (size_t)t * HW] - m);
    if (iscol) {
        cmax[idx] = m;
        csuminv[idx] = 1.0f / s;
    } else {
        rmax[idx] = m;
        rsuminv[idx] = 1.0f / s;
    }
}

// ---------------- Kernel 3: P = exp(2x-rm-cm)*rsinv*csinv, transposed write ----------------
__global__ __launch_bounds__(256) void final_kernel(const float* __restrict__ N,
                                                    const float* __restrict__ rm,
                                                    const float* __restrict__ rsi,
                                                    const float* __restrict__ cm,
                                                    const float* __restrict__ csi,
                                                    float* __restrict__ out) {
    int blk = blockIdx.x;
    int b = blk >> 8;
    int tile = blk & 255;
    int i0 = (tile >> 4) * 64;
    int k0 = (tile & 15) * 64;
    const float* Nb = N + (size_t)b * HW * HW;
    float* outb = out + (size_t)b * HW * HW;
    const float* rmb = rm + b * HW;
    const float* rsib = rsi + b * HW;
    const float* cmb = cm + b * HW;
    const float* csib = csi + b * HW;

    __shared__ float tileP[64][65];

    int t = threadIdx.x;
    int tr = t >> 4;
    int tc4 = (t & 15) * 4;

    float4 cm4 = *reinterpret_cast<const float4*>(&cmb[k0 + tc4]);
    float4 cs4 = *reinterpret_cast<const float4*>(&csib[k0 + tc4]);
    float cmv[4] = {cm4.x, cm4.y, cm4.z, cm4.w};
    float csv[4] = {cs4.x, cs4.y, cs4.z, cs4.w};

#pragma unroll
    for (int rr = 0; rr < 4; ++rr) {
        int il = tr + rr * 16;
        int i = i0 + il;
        float rmax = rmb[i];
        float rsinv = rsib[i];
        float4 v = *reinterpret_cast<const float4*>(&Nb[(size_t)i * HW + k0 + tc4]);
        float x[4] = {v.x, v.y, v.z, v.w};
#pragma unroll
        for (int j = 0; j < 4; ++j) {
            tileP[il][tc4 + j] = __expf(x[j] + x[j] - rmax - cmv[j]) * rsinv * csv[j];
        }
    }
    __syncthreads();
#pragma unroll
    for (int rr = 0; rr < 4; ++rr) {
        int kl = tr + rr * 16;
        int k = k0 + kl;
        int tk = ((k & 31) << 5) | (k >> 5);
        float4 v;
        v.x = tileP[tc4 + 0][kl];
        v.y = tileP[tc4 + 1][kl];
        v.z = tileP[tc4 + 2][kl];
        v.w = tileP[tc4 + 3][kl];
        *reinterpret_cast<float4*>(&outb[(size_t)tk * HW + i0 + tc4]) = v;
    }
}

extern "C" void kernel_launch(void* const* d_in, const int* in_sizes, int n_in,
                              void* d_out, int out_size, void* d_ws, size_t ws_size,
                              hipStream_t stream) {
    const float* A = (const float*)d_in[0];   // feature_A [32,256,32,32]
    const float* Bm = (const float*)d_in[1];  // feature_B [32,256,32,32]
    float* out = (float*)d_out;

    float* ws = (float*)d_ws;
    const size_t n_elems = (size_t)NB * HW * HW;       // 33.5M
    const size_t stat_n = (size_t)NB * HW;             // 32768
    const size_t part_n = (size_t)NB * 16 * HW;        // 524288
    float* N = ws;
    float* rmax = N + n_elems;
    float* rsuminv = rmax + stat_n;
    float* cmax = rsuminv + stat_n;
    float* csuminv = cmax + stat_n;
    float* rpm = csuminv + stat_n;
    float* rps = rpm + part_n;
    float* cpm = rps + part_n;
    float* cps = cpm + part_n;
    ushort* Qhi = (ushort*)(cps + part_n);             // feature_A^T bf16 hi
    ushort* Qlo = Qhi + (size_t)NB * HW * CC;
    ushort* Phi = Qlo + (size_t)NB * HW * CC;          // feature_B^T bf16 hi
    ushort* Plo = Phi + (size_t)NB * HW * CC;

    hipLaunchKernelGGL(convert_kernel, dim3(2 * NB * 64), dim3(256), 0, stream,
                       A, Bm, Qhi, Qlo, Phi, Plo);
    hipLaunchKernelGGL(gemm_mfma, dim3(NB * 64), dim3(256), 0, stream,
                       Phi, Plo, Qhi, Qlo, N, rpm, rps, cpm, cps);
    hipLaunchKernelGGL(combine_kernel, dim3(256), dim3(256), 0, stream,
                       rpm, rps, cpm, cps, rmax, rsuminv, cmax, csuminv);
    hipLaunchKernelGGL(final_kernel, dim3(NB * 256), dim3(256), 0, stream,
                       N, rmax, rsuminv, cmax, csuminv, out);
}